// Round 8
// baseline (1375.403 us; speedup 1.0000x reference)
//
#include <hip/hip_runtime.h>
#include <stdint.h>
#include <stddef.h>

// W4A8 fake-quant SwiGLU MLP for MI355X (gfx950).
// Exact-integer reformulation: fake-quant values are int*scale, so every
// matmul is an int8 x int4 integer GEMM (exact in i32/f32) times rank-1 scales.
// GEMMs: mfma_i32_32x32x32_i8 (R8), global_load_lds width-16,
// XOR-swizzled LDS (slot = (chunk + (row>>1)) & 3) for conflict-free b128 reads.
//
// R1: gemm1 launch-bounds spill fix (2700 -> 527 us).
// R2: XCD swizzle + n-major raster (527 -> 499) -- best measured gemm1.
// R3: gemm2 128x256; merged quant launches. R4: dbuf REGRESS (vmcnt0 drain).
// R5: coarse counted-vmcnt NULL. R6: 8-phase i8 REGRESS (phase overhead).
// R7: m-major raster: FETCH 1.44->0.50 GB but dur 499->576 -- gemm1 is NOT
//     HBM-bound; n-major channel-spread helps a latency-bound kernel.
// R8: revert to n-major; switch both GEMMs to mfma_i32_32x32x32_i8:
//     same LDS bytes/K-step, HALF the MFMA instructions, +12% matrix-pipe
//     rate (4404 vs 3944 TOPS ubench). A/B frag: row/col=lane&31,
//     k=(lane>>5)*16+j -> one swizzled 16B chunk, chunk = ks*2+(lane>>5).
//     C/D: col=lane&31, row=(reg&3)+8*(reg>>2)+4*(lane>>5).

using i32x4 = __attribute__((ext_vector_type(4))) int;
using i32x16 = __attribute__((ext_vector_type(16))) int;

#define BM 128
#define BN 128
#define BN2 256
#define BK 64

__device__ __forceinline__ void gl2lds16(const void* gptr, void* lptr) {
  __builtin_amdgcn_global_load_lds(
      (const __attribute__((address_space(1))) uint32_t*)gptr,
      (__attribute__((address_space(3))) uint32_t*)lptr, 16, 0, 0);
}

// ---------------------------------------------------------------------------
// Merged per-row symmetric fake-quant for all four inputs in ONE launch.
// blockIdx segments: [0,4096) x | [4096,15104) Wg | [15104,26112) Wu |
// [26112,30208) Wd. Also zero-inits hmax[row] in the x segment.
// ---------------------------------------------------------------------------
__global__ void quant_all_kernel(
    const float* __restrict__ x, const float* __restrict__ Wg,
    const float* __restrict__ Wu, const float* __restrict__ Wd,
    int8_t* __restrict__ xq, int8_t* __restrict__ wgq,
    int8_t* __restrict__ wuq, int8_t* __restrict__ wdq,
    float* __restrict__ sx, float* __restrict__ swg,
    float* __restrict__ swu, float* __restrict__ swd,
    int* __restrict__ hmax) {
  const int b = blockIdx.x;
  const float* src;
  int8_t* dst;
  float* scales;
  int cols, row;
  float qmax, qmin;
  if (b < 4096) {
    src = x; dst = xq; scales = sx; cols = 4096; row = b;
    qmax = 127.0f; qmin = -128.0f;
    if (threadIdx.x == 0) hmax[row] = 0;  // init for gemm1's atomicMax
  } else if (b < 4096 + 11008) {
    src = Wg; dst = wgq; scales = swg; cols = 4096; row = b - 4096;
    qmax = 7.0f; qmin = -8.0f;
  } else if (b < 4096 + 22016) {
    src = Wu; dst = wuq; scales = swu; cols = 4096; row = b - 15104;
    qmax = 7.0f; qmin = -8.0f;
  } else {
    src = Wd; dst = wdq; scales = swd; cols = 11008; row = b - 26112;
    qmax = 7.0f; qmin = -8.0f;
  }
  const int n4 = cols >> 2;
  const float4* s4 = (const float4*)(src + (size_t)row * cols);
  float amax = 0.0f;
  for (int i = threadIdx.x; i < n4; i += blockDim.x) {
    float4 v = s4[i];
    amax = fmaxf(amax, fmaxf(fmaxf(fabsf(v.x), fabsf(v.y)),
                             fmaxf(fabsf(v.z), fabsf(v.w))));
  }
#pragma unroll
  for (int off = 32; off > 0; off >>= 1)
    amax = fmaxf(amax, __shfl_xor(amax, off, 64));
  __shared__ float wmax[4];
  if ((threadIdx.x & 63) == 0) wmax[threadIdx.x >> 6] = amax;
  __syncthreads();
  const float scale =
      fmaxf(fmaxf(fmaxf(wmax[0], wmax[1]), fmaxf(wmax[2], wmax[3])) / qmax,
            1e-8f);
  if (threadIdx.x == 0) scales[row] = scale;
  char4* d4 = (char4*)(dst + (size_t)row * cols);
  for (int i = threadIdx.x; i < n4; i += blockDim.x) {
    float4 v = s4[i];
    char4 q;
    q.x = (char)(int)fminf(fmaxf(rintf(v.x / scale), qmin), qmax);
    q.y = (char)(int)fminf(fmaxf(rintf(v.y / scale), qmin), qmax);
    q.z = (char)(int)fminf(fmaxf(rintf(v.z / scale), qmin), qmax);
    q.w = (char)(int)fminf(fmaxf(rintf(v.w / scale), qmin), qmax);
    d4[i] = q;
  }
}

// Single-pass per-row quant of h: absmax comes from gemm1's fused atomicMax.
__global__ void quant_h_kernel(const float* __restrict__ h,
                               int8_t* __restrict__ hq,
                               float* __restrict__ sh,
                               const int* __restrict__ hmax, int cols) {
  const int row = blockIdx.x;
  const float amax = __int_as_float(hmax[row]);
  const float scale = fmaxf(amax / 127.0f, 1e-8f);
  if (threadIdx.x == 0) sh[row] = scale;
  const int n4 = cols >> 2;
  const float4* s4 = (const float4*)(h + (size_t)row * cols);
  char4* d4 = (char4*)(hq + (size_t)row * cols);
  for (int i = threadIdx.x; i < n4; i += blockDim.x) {
    float4 v = s4[i];
    char4 q;
    q.x = (char)(int)fminf(fmaxf(rintf(v.x / scale), -128.0f), 127.0f);
    q.y = (char)(int)fminf(fmaxf(rintf(v.y / scale), -128.0f), 127.0f);
    q.z = (char)(int)fminf(fmaxf(rintf(v.z / scale), -128.0f), 127.0f);
    q.w = (char)(int)fminf(fmaxf(rintf(v.w / scale), -128.0f), 127.0f);
    d4[i] = q;
  }
}

// Bijective XCD-aware remap of the linear block id (requires nwg % 8 == 0).
__device__ __forceinline__ int xcd_swizzle(int lid, int nwg) {
  const int cpx = nwg >> 3;
  return (lid & 7) * cpx + (lid >> 3);
}

// Swizzled 16B-chunk LDS read: source chunk q of row r lives at slot
// (q + (r>>1)) & 3.
__device__ __forceinline__ i32x4 lds_frag(const int8_t* base, int row,
                                          int chunk) {
  return *(const i32x4*)(base + row * BK + (((chunk + (row >> 1)) & 3) << 4));
}

// Fused gate+up GEMM: acc_g = xq @ Wg^T, acc_u = xq @ Wu^T (int32 exact),
// epilogue h = silu(acc_g*sx*swg) * (acc_u*sx*swu) -> hbuf (f32),
// plus per-row |h| max -> atomicMax(hmax[row]).
// mfma_i32_32x32x32_i8: per wave 2x2 32x32 tiles per matrix.
__global__ __launch_bounds__(256, 2) void gemm1_kernel(
    const int8_t* __restrict__ xq, const int8_t* __restrict__ wgq,
    const int8_t* __restrict__ wuq, const float* __restrict__ sx,
    const float* __restrict__ swg, const float* __restrict__ swu,
    float* __restrict__ hbuf, int* __restrict__ hmax, int M, int N, int K) {
  __shared__ __align__(16) int8_t sA[BM * BK];
  __shared__ __align__(16) int8_t sBg[BN * BK];
  __shared__ __align__(16) int8_t sBu[BN * BK];

  const int tid = threadIdx.x;
  const int lane = tid & 63;
  const int l31 = lane & 31;
  const int half = lane >> 5;
  const int wave = tid >> 6;
  const int wm = wave >> 1;
  const int wn = wave & 1;

  const int nwg = gridDim.x * gridDim.y;
  const int lid = xcd_swizzle(blockIdx.y * gridDim.x + blockIdx.x, nwg);
  const int n0 = (lid % gridDim.x) * BN;  // n-major (R2 best)
  const int m0 = (lid / gridDim.x) * BM;

  i32x16 accg[2][2] = {};
  i32x16 accu[2][2] = {};

  for (int k0 = 0; k0 < K; k0 += BK) {
#pragma unroll
    for (int it = 0; it < 2; ++it) {
      const int c = tid + it * 256;   // 512 16B chunks per 128x64 tile
      const int r = c >> 2;           // tile row
      const int s = c & 3;            // LDS slot within row
      const int kc = ((s - (r >> 1)) & 3) << 4;  // XOR-swizzled source chunk
      gl2lds16(xq  + (size_t)(m0 + r) * K + (k0 + kc), sA  + c * 16);
      gl2lds16(wgq + (size_t)(n0 + r) * K + (k0 + kc), sBg + c * 16);
      gl2lds16(wuq + (size_t)(n0 + r) * K + (k0 + kc), sBu + c * 16);
    }
    __syncthreads();

    // A frags: row = wm*64 + i*32 + l31, k-chunk = ks*2 + half
    i32x4 af[2][2], bg[2][2], bu[2][2];
#pragma unroll
    for (int i = 0; i < 2; ++i)
#pragma unroll
      for (int ks = 0; ks < 2; ++ks)
        af[i][ks] = lds_frag(sA, wm * 64 + i * 32 + l31, ks * 2 + half);
#pragma unroll
    for (int j = 0; j < 2; ++j)
#pragma unroll
      for (int ks = 0; ks < 2; ++ks) {
        bg[j][ks] = lds_frag(sBg, wn * 64 + j * 32 + l31, ks * 2 + half);
        bu[j][ks] = lds_frag(sBu, wn * 64 + j * 32 + l31, ks * 2 + half);
      }
#pragma unroll
    for (int ks = 0; ks < 2; ++ks)
#pragma unroll
      for (int i = 0; i < 2; ++i)
#pragma unroll
        for (int j = 0; j < 2; ++j) {
          accg[i][j] = __builtin_amdgcn_mfma_i32_32x32x32_i8(
              af[i][ks], bg[j][ks], accg[i][j], 0, 0, 0);
          accu[i][j] = __builtin_amdgcn_mfma_i32_32x32x32_i8(
              af[i][ks], bu[j][ks], accu[i][j], 0, 0, 0);
        }
    __syncthreads();
  }

  // epilogue: C/D layout col=lane&31, row=(r&3)+8*(r>>2)+4*half
  float sg[2], su[2];
#pragma unroll
  for (int j = 0; j < 2; ++j) {
    const int col = n0 + wn * 64 + j * 32 + l31;
    sg[j] = swg[col];
    su[j] = swu[col];
  }
#pragma unroll
  for (int i = 0; i < 2; ++i) {
#pragma unroll
    for (int r = 0; r < 16; ++r) {
      const int row =
          m0 + wm * 64 + i * 32 + (r & 3) + 8 * (r >> 2) + 4 * half;
      const float s_x = sx[row];
      float rmax = 0.0f;
#pragma unroll
      for (int j = 0; j < 2; ++j) {
        const int col = n0 + wn * 64 + j * 32 + l31;
        const float g = (float)accg[i][j][r] * s_x * sg[j];
        const float u = (float)accu[i][j][r] * s_x * su[j];
        const float hv = (g / (1.0f + expf(-g))) * u;  // silu(g)*u
        hbuf[(size_t)row * N + col] = hv;
        rmax = fmaxf(rmax, fabsf(hv));
      }
      // reduce |h| max across the 32 lanes of this half (same row)
#pragma unroll
      for (int off = 16; off > 0; off >>= 1)
        rmax = fmaxf(rmax, __shfl_xor(rmax, off, 64));
      if (l31 == 0)
        atomicMax(hmax + row, __float_as_int(rmax));  // nonneg f32: int-mono
    }
  }
}

// Down-projection GEMM: out = (hq @ Wd^T) * sh[m] * swd[n]
// 128x256 tile, per-wave 64x128 = 2x4 32x32 tiles (acc 128 VGPR).
__global__ __launch_bounds__(256, 2) void gemm2_kernel(
    const int8_t* __restrict__ hq, const int8_t* __restrict__ wdq,
    const float* __restrict__ sh, const float* __restrict__ swd,
    float* __restrict__ out, int M, int N, int K) {
  __shared__ __align__(16) int8_t sA[BM * BK];    // 8 KB
  __shared__ __align__(16) int8_t sB[BN2 * BK];   // 16 KB

  const int tid = threadIdx.x;
  const int lane = tid & 63;
  const int l31 = lane & 31;
  const int half = lane >> 5;
  const int wave = tid >> 6;
  const int wm = wave >> 1;   // 0..1: 64-row group
  const int wn = wave & 1;    // 0..1: 128-col group

  const int nwg = gridDim.x * gridDim.y;
  const int lid = xcd_swizzle(blockIdx.y * gridDim.x + blockIdx.x, nwg);
  const int n0 = (lid % gridDim.x) * BN2;  // n-major
  const int m0 = (lid / gridDim.x) * BM;

  i32x16 acc[2][4] = {};

  for (int k0 = 0; k0 < K; k0 += BK) {
#pragma unroll
    for (int it = 0; it < 2; ++it) {  // A tile: 512 chunks
      const int c = tid + it * 256;
      const int r = c >> 2;
      const int s = c & 3;
      const int kc = ((s - (r >> 1)) & 3) << 4;
      gl2lds16(hq + (size_t)(m0 + r) * K + (k0 + kc), sA + c * 16);
    }
#pragma unroll
    for (int it = 0; it < 4; ++it) {  // B tile: 1024 chunks (256 rows)
      const int c = tid + it * 256;
      const int r = c >> 2;
      const int s = c & 3;
      const int kc = ((s - (r >> 1)) & 3) << 4;
      gl2lds16(wdq + (size_t)(n0 + r) * K + (k0 + kc), sB + c * 16);
    }
    __syncthreads();

    i32x4 af[2][2], bf[4][2];
#pragma unroll
    for (int i = 0; i < 2; ++i)
#pragma unroll
      for (int ks = 0; ks < 2; ++ks)
        af[i][ks] = lds_frag(sA, wm * 64 + i * 32 + l31, ks * 2 + half);
#pragma unroll
    for (int j = 0; j < 4; ++j)
#pragma unroll
      for (int ks = 0; ks < 2; ++ks)
        bf[j][ks] = lds_frag(sB, wn * 128 + j * 32 + l31, ks * 2 + half);
#pragma unroll
    for (int ks = 0; ks < 2; ++ks)
#pragma unroll
      for (int i = 0; i < 2; ++i)
#pragma unroll
        for (int j = 0; j < 4; ++j)
          acc[i][j] = __builtin_amdgcn_mfma_i32_32x32x32_i8(
              af[i][ks], bf[j][ks], acc[i][j], 0, 0, 0);
    __syncthreads();
  }

  float sn[4];
#pragma unroll
  for (int j = 0; j < 4; ++j) sn[j] = swd[n0 + wn * 128 + j * 32 + l31];
#pragma unroll
  for (int i = 0; i < 2; ++i) {
#pragma unroll
    for (int r = 0; r < 16; ++r) {
      const int row =
          m0 + wm * 64 + i * 32 + (r & 3) + 8 * (r >> 2) + 4 * half;
      const float s_m = sh[row];
#pragma unroll
      for (int j = 0; j < 4; ++j) {
        const int col = n0 + wn * 128 + j * 32 + l31;
        out[(size_t)row * N + col] = (float)acc[i][j][r] * s_m * sn[j];
      }
    }
  }
}

extern "C" void kernel_launch(void* const* d_in, const int* in_sizes, int n_in,
                              void* d_out, int out_size, void* d_ws, size_t ws_size,
                              hipStream_t stream) {
  const float* x  = (const float*)d_in[0];   // [2,2048,4096]
  const float* Wg = (const float*)d_in[1];   // [11008,4096]
  const float* Wu = (const float*)d_in[2];   // [11008,4096]
  const float* Wd = (const float*)d_in[3];   // [4096,11008]
  float* out = (float*)d_out;                // [2,2048,4096] f32

  const int M = 4096;   // B*S
  const int D = 4096;
  const int F = 11008;

  // workspace layout (~378 MB total), all offsets 16B-aligned
  uint8_t* ws = (uint8_t*)d_ws;
  size_t off = 0;
  int8_t* xq  = (int8_t*)(ws + off); off += (size_t)M * D;      // 16 MB
  int8_t* wgq = (int8_t*)(ws + off); off += (size_t)F * D;      // 45 MB
  int8_t* wuq = (int8_t*)(ws + off); off += (size_t)F * D;      // 45 MB
  int8_t* wdq = (int8_t*)(ws + off); off += (size_t)D * F;      // 45 MB
  int8_t* hq  = (int8_t*)(ws + off); off += (size_t)M * F;      // 45 MB
  float* hbuf = (float*)(ws + off);  off += (size_t)M * F * 4;  // 180 MB
  float* sx   = (float*)(ws + off);  off += (size_t)M * 4;
  float* swg  = (float*)(ws + off);  off += (size_t)F * 4;
  float* swu  = (float*)(ws + off);  off += (size_t)F * 4;
  float* swd  = (float*)(ws + off);  off += (size_t)D * 4;
  float* sh   = (float*)(ws + off);  off += (size_t)M * 4;
  int*   hmax = (int*)(ws + off);    off += (size_t)M * 4;

  hipLaunchKernelGGL(quant_all_kernel, dim3(M + F + F + D), dim3(256), 0,
                     stream, x, Wg, Wu, Wd, xq, wgq, wuq, wdq,
                     sx, swg, swu, swd, hmax);
  hipLaunchKernelGGL(gemm1_kernel, dim3(F / BN, M / BM), dim3(256), 0, stream,
                     xq, wgq, wuq, sx, swg, swu, hbuf, hmax, M, F, D);
  hipLaunchKernelGGL(quant_h_kernel, dim3(M), dim3(256), 0, stream,
                     hbuf, hq, sh, hmax, F);
  hipLaunchKernelGGL(gemm2_kernel, dim3(D / BN2, M / BM), dim3(256), 0, stream,
                     hq, wdq, sh, swd, out, M, D, F);
}

// Round 9
// 1240.641 us; speedup vs baseline: 1.1086x; 1.1086x over previous
//
#include <hip/hip_runtime.h>
#include <stdint.h>
#include <stddef.h>

// W4A8 fake-quant SwiGLU MLP for MI355X (gfx950).
// Exact-integer reformulation: fake-quant values are int*scale, so every
// matmul is an int8 x int4 integer GEMM (exact in i32/f32) times rank-1 scales.
// GEMMs: mfma_i32_16x16x64_i8, global_load_lds width-16, BK=128 with
// 8-slot XOR swizzle (slot = (chunk + row) & 7) for conflict-free b128 reads.
//
// R1: gemm1 launch-bounds spill fix (2700 -> 527 us).
// R2: XCD swizzle + n-major raster (527 -> 499) -- best measured gemm1.
// R3: gemm2 128x256; merged quant launches (total 1274, session best).
// R4: dbuf REGRESS (vmcnt0 drain). R5: coarse counted-vmcnt NULL.
// R6: 8-phase i8 REGRESS (phase overhead). R7: m-major REGRESS (not HBM-bound).
// R8: mfma 32x32x32 REGRESS: frag pattern (32 rows/fixed chunk) breaks the
//     4-slot swizzle -> 3.4e7 bank conflicts. Reverted to 16x16x64.
// R9: BK 64 -> 128: halves the per-K-step barrier+vmcnt(0)-drain count
//     (the one confirmed structural cost), same bytes & regs, 48 KB LDS
//     still 2 blocks/CU. New 8-slot swizzle for the 128B row.

using i32x4 = __attribute__((ext_vector_type(4))) int;

#define BM 128
#define BN 128
#define BN2 256
#define BK 128

__device__ __forceinline__ void gl2lds16(const void* gptr, void* lptr) {
  __builtin_amdgcn_global_load_lds(
      (const __attribute__((address_space(1))) uint32_t*)gptr,
      (__attribute__((address_space(3))) uint32_t*)lptr, 16, 0, 0);
}

// ---------------------------------------------------------------------------
// Merged per-row symmetric fake-quant for all four inputs in ONE launch.
// blockIdx segments: [0,4096) x | [4096,15104) Wg | [15104,26112) Wu |
// [26112,30208) Wd. Also zero-inits hmax[row] in the x segment.
// ---------------------------------------------------------------------------
__global__ void quant_all_kernel(
    const float* __restrict__ x, const float* __restrict__ Wg,
    const float* __restrict__ Wu, const float* __restrict__ Wd,
    int8_t* __restrict__ xq, int8_t* __restrict__ wgq,
    int8_t* __restrict__ wuq, int8_t* __restrict__ wdq,
    float* __restrict__ sx, float* __restrict__ swg,
    float* __restrict__ swu, float* __restrict__ swd,
    int* __restrict__ hmax) {
  const int b = blockIdx.x;
  const float* src;
  int8_t* dst;
  float* scales;
  int cols, row;
  float qmax, qmin;
  if (b < 4096) {
    src = x; dst = xq; scales = sx; cols = 4096; row = b;
    qmax = 127.0f; qmin = -128.0f;
    if (threadIdx.x == 0) hmax[row] = 0;  // init for gemm1's atomicMax
  } else if (b < 4096 + 11008) {
    src = Wg; dst = wgq; scales = swg; cols = 4096; row = b - 4096;
    qmax = 7.0f; qmin = -8.0f;
  } else if (b < 4096 + 22016) {
    src = Wu; dst = wuq; scales = swu; cols = 4096; row = b - 15104;
    qmax = 7.0f; qmin = -8.0f;
  } else {
    src = Wd; dst = wdq; scales = swd; cols = 11008; row = b - 26112;
    qmax = 7.0f; qmin = -8.0f;
  }
  const int n4 = cols >> 2;
  const float4* s4 = (const float4*)(src + (size_t)row * cols);
  float amax = 0.0f;
  for (int i = threadIdx.x; i < n4; i += blockDim.x) {
    float4 v = s4[i];
    amax = fmaxf(amax, fmaxf(fmaxf(fabsf(v.x), fabsf(v.y)),
                             fmaxf(fabsf(v.z), fabsf(v.w))));
  }
#pragma unroll
  for (int off = 32; off > 0; off >>= 1)
    amax = fmaxf(amax, __shfl_xor(amax, off, 64));
  __shared__ float wmax[4];
  if ((threadIdx.x & 63) == 0) wmax[threadIdx.x >> 6] = amax;
  __syncthreads();
  const float scale =
      fmaxf(fmaxf(fmaxf(wmax[0], wmax[1]), fmaxf(wmax[2], wmax[3])) / qmax,
            1e-8f);
  if (threadIdx.x == 0) scales[row] = scale;
  char4* d4 = (char4*)(dst + (size_t)row * cols);
  for (int i = threadIdx.x; i < n4; i += blockDim.x) {
    float4 v = s4[i];
    char4 q;
    q.x = (char)(int)fminf(fmaxf(rintf(v.x / scale), qmin), qmax);
    q.y = (char)(int)fminf(fmaxf(rintf(v.y / scale), qmin), qmax);
    q.z = (char)(int)fminf(fmaxf(rintf(v.z / scale), qmin), qmax);
    q.w = (char)(int)fminf(fmaxf(rintf(v.w / scale), qmin), qmax);
    d4[i] = q;
  }
}

// Single-pass per-row quant of h: absmax comes from gemm1's fused atomicMax.
__global__ void quant_h_kernel(const float* __restrict__ h,
                               int8_t* __restrict__ hq,
                               float* __restrict__ sh,
                               const int* __restrict__ hmax, int cols) {
  const int row = blockIdx.x;
  const float amax = __int_as_float(hmax[row]);
  const float scale = fmaxf(amax / 127.0f, 1e-8f);
  if (threadIdx.x == 0) sh[row] = scale;
  const int n4 = cols >> 2;
  const float4* s4 = (const float4*)(h + (size_t)row * cols);
  char4* d4 = (char4*)(hq + (size_t)row * cols);
  for (int i = threadIdx.x; i < n4; i += blockDim.x) {
    float4 v = s4[i];
    char4 q;
    q.x = (char)(int)fminf(fmaxf(rintf(v.x / scale), -128.0f), 127.0f);
    q.y = (char)(int)fminf(fmaxf(rintf(v.y / scale), -128.0f), 127.0f);
    q.z = (char)(int)fminf(fmaxf(rintf(v.z / scale), -128.0f), 127.0f);
    q.w = (char)(int)fminf(fmaxf(rintf(v.w / scale), -128.0f), 127.0f);
    d4[i] = q;
  }
}

// Bijective XCD-aware remap of the linear block id (requires nwg % 8 == 0).
__device__ __forceinline__ int xcd_swizzle(int lid, int nwg) {
  const int cpx = nwg >> 3;
  return (lid & 7) * cpx + (lid >> 3);
}

// 8-slot swizzled 16B-chunk LDS read (BK=128): source chunk q of row r is
// stored at slot (q + r) & 7.
__device__ __forceinline__ i32x4 lds_frag(const int8_t* base, int row,
                                          int chunk) {
  return *(const i32x4*)(base + row * BK + (((chunk + row) & 7) << 4));
}

// Fused gate+up GEMM: acc_g = xq @ Wg^T, acc_u = xq @ Wu^T (int32 exact),
// epilogue h = silu(acc_g*sx*swg) * (acc_u*sx*swu) -> hbuf (f32),
// plus per-row |h| max -> atomicMax(hmax[row]).
// BK=128: one stage + 2 barriers per 128-K (half the drains of BK=64).
__global__ __launch_bounds__(256, 2) void gemm1_kernel(
    const int8_t* __restrict__ xq, const int8_t* __restrict__ wgq,
    const int8_t* __restrict__ wuq, const float* __restrict__ sx,
    const float* __restrict__ swg, const float* __restrict__ swu,
    float* __restrict__ hbuf, int* __restrict__ hmax, int M, int N, int K) {
  __shared__ __align__(16) int8_t sA[BM * BK];    // 16 KB
  __shared__ __align__(16) int8_t sBg[BN * BK];   // 16 KB
  __shared__ __align__(16) int8_t sBu[BN * BK];   // 16 KB

  const int tid = threadIdx.x;
  const int lane = tid & 63;
  const int quad = lane >> 4;
  const int l16 = lane & 15;
  const int wave = tid >> 6;
  const int wm = wave >> 1;
  const int wn = wave & 1;

  const int nwg = gridDim.x * gridDim.y;
  const int lid = xcd_swizzle(blockIdx.y * gridDim.x + blockIdx.x, nwg);
  const int n0 = (lid % gridDim.x) * BN;  // n-major (R2 best)
  const int m0 = (lid / gridDim.x) * BM;

  i32x4 accg[4][4] = {};
  i32x4 accu[4][4] = {};

  for (int k0 = 0; k0 < K; k0 += BK) {
#pragma unroll
    for (int it = 0; it < 4; ++it) {
      const int c = tid + it * 256;   // 1024 16B chunks per 128x128 tile
      const int r = c >> 3;           // tile row (8 chunks/row)
      const int s = c & 7;            // LDS slot within row
      const int kc = ((s - r) & 7) << 4;  // XOR-swizzled source chunk
      gl2lds16(xq  + (size_t)(m0 + r) * K + (k0 + kc), sA  + c * 16);
      gl2lds16(wgq + (size_t)(n0 + r) * K + (k0 + kc), sBg + c * 16);
      gl2lds16(wuq + (size_t)(n0 + r) * K + (k0 + kc), sBu + c * 16);
    }
    __syncthreads();

#pragma unroll
    for (int ks = 0; ks < 2; ++ks) {   // two 64-wide sub-steps
      const int c8 = ks * 4 + quad;    // 16B chunk within the row
      i32x4 af[4];
#pragma unroll
      for (int i = 0; i < 4; ++i)
        af[i] = lds_frag(sA, wm * 64 + i * 16 + l16, c8);
#pragma unroll
      for (int j = 0; j < 4; ++j) {
        const int br = wn * 64 + j * 16 + l16;
        i32x4 bg = lds_frag(sBg, br, c8);
        i32x4 bu = lds_frag(sBu, br, c8);
#pragma unroll
        for (int i = 0; i < 4; ++i) {
          accg[i][j] = __builtin_amdgcn_mfma_i32_16x16x64_i8(af[i], bg, accg[i][j], 0, 0, 0);
          accu[i][j] = __builtin_amdgcn_mfma_i32_16x16x64_i8(af[i], bu, accu[i][j], 0, 0, 0);
        }
      }
    }
    __syncthreads();
  }

  float sg[4], su[4];
#pragma unroll
  for (int j = 0; j < 4; ++j) {
    const int col = n0 + wn * 64 + j * 16 + l16;
    sg[j] = swg[col];
    su[j] = swu[col];
  }
#pragma unroll
  for (int i = 0; i < 4; ++i) {
#pragma unroll
    for (int r = 0; r < 4; ++r) {
      const int row = m0 + wm * 64 + i * 16 + quad * 4 + r;
      const float s_x = sx[row];
      float rmax = 0.0f;
#pragma unroll
      for (int j = 0; j < 4; ++j) {
        const int col = n0 + wn * 64 + j * 16 + l16;
        const float g = (float)accg[i][j][r] * s_x * sg[j];
        const float u = (float)accu[i][j][r] * s_x * su[j];
        const float hv = (g / (1.0f + expf(-g))) * u;  // silu(g)*u
        hbuf[(size_t)row * N + col] = hv;
        rmax = fmaxf(rmax, fabsf(hv));
      }
      // reduce |h| max across the 16 lanes holding this row's columns
#pragma unroll
      for (int off = 8; off > 0; off >>= 1)
        rmax = fmaxf(rmax, __shfl_xor(rmax, off, 64));
      if (l16 == 0)
        atomicMax(hmax + row, __float_as_int(rmax));  // nonneg f32: int-mono
    }
  }
}

// Down-projection GEMM: out = (hq @ Wd^T) * sh[m] * swd[n]
// 128x256 tile, per-wave 64x128 (acc[4][8] = 128 VGPR), BK=128.
__global__ __launch_bounds__(256, 2) void gemm2_kernel(
    const int8_t* __restrict__ hq, const int8_t* __restrict__ wdq,
    const float* __restrict__ sh, const float* __restrict__ swd,
    float* __restrict__ out, int M, int N, int K) {
  __shared__ __align__(16) int8_t sA[BM * BK];    // 16 KB
  __shared__ __align__(16) int8_t sB[BN2 * BK];   // 32 KB

  const int tid = threadIdx.x;
  const int lane = tid & 63;
  const int quad = lane >> 4;
  const int l16 = lane & 15;
  const int wave = tid >> 6;
  const int wm = wave >> 1;   // 0..1: 64-row group
  const int wn = wave & 1;    // 0..1: 128-col group

  const int nwg = gridDim.x * gridDim.y;
  const int lid = xcd_swizzle(blockIdx.y * gridDim.x + blockIdx.x, nwg);
  const int n0 = (lid % gridDim.x) * BN2;  // n-major
  const int m0 = (lid / gridDim.x) * BM;

  i32x4 acc[4][8] = {};

  for (int k0 = 0; k0 < K; k0 += BK) {
#pragma unroll
    for (int it = 0; it < 4; ++it) {  // A tile: 1024 chunks
      const int c = tid + it * 256;
      const int r = c >> 3;
      const int s = c & 7;
      const int kc = ((s - r) & 7) << 4;
      gl2lds16(hq + (size_t)(m0 + r) * K + (k0 + kc), sA + c * 16);
    }
#pragma unroll
    for (int it = 0; it < 8; ++it) {  // B tile: 2048 chunks (256 rows)
      const int c = tid + it * 256;
      const int r = c >> 3;
      const int s = c & 7;
      const int kc = ((s - r) & 7) << 4;
      gl2lds16(wdq + (size_t)(n0 + r) * K + (k0 + kc), sB + c * 16);
    }
    __syncthreads();

#pragma unroll
    for (int ks = 0; ks < 2; ++ks) {
      const int c8 = ks * 4 + quad;
      i32x4 af[4];
#pragma unroll
      for (int i = 0; i < 4; ++i)
        af[i] = lds_frag(sA, wm * 64 + i * 16 + l16, c8);
#pragma unroll
      for (int j = 0; j < 8; ++j) {
        i32x4 bf = lds_frag(sB, wn * 128 + j * 16 + l16, c8);
#pragma unroll
        for (int i = 0; i < 4; ++i)
          acc[i][j] = __builtin_amdgcn_mfma_i32_16x16x64_i8(af[i], bf, acc[i][j], 0, 0, 0);
      }
    }
    __syncthreads();
  }

  float sn[8];
#pragma unroll
  for (int j = 0; j < 8; ++j) sn[j] = swd[n0 + wn * 128 + j * 16 + l16];
#pragma unroll
  for (int i = 0; i < 4; ++i) {
#pragma unroll
    for (int r = 0; r < 4; ++r) {
      const int row = m0 + wm * 64 + i * 16 + quad * 4 + r;
      const float s_m = sh[row];
#pragma unroll
      for (int j = 0; j < 8; ++j) {
        const int col = n0 + wn * 128 + j * 16 + l16;
        out[(size_t)row * N + col] = (float)acc[i][j][r] * s_m * sn[j];
      }
    }
  }
}

extern "C" void kernel_launch(void* const* d_in, const int* in_sizes, int n_in,
                              void* d_out, int out_size, void* d_ws, size_t ws_size,
                              hipStream_t stream) {
  const float* x  = (const float*)d_in[0];   // [2,2048,4096]
  const float* Wg = (const float*)d_in[1];   // [11008,4096]
  const float* Wu = (const float*)d_in[2];   // [11008,4096]
  const float* Wd = (const float*)d_in[3];   // [4096,11008]
  float* out = (float*)d_out;                // [2,2048,4096] f32

  const int M = 4096;   // B*S
  const int D = 4096;
  const int F = 11008;

  // workspace layout (~378 MB total), all offsets 16B-aligned
  uint8_t* ws = (uint8_t*)d_ws;
  size_t off = 0;
  int8_t* xq  = (int8_t*)(ws + off); off += (size_t)M * D;      // 16 MB
  int8_t* wgq = (int8_t*)(ws + off); off += (size_t)F * D;      // 45 MB
  int8_t* wuq = (int8_t*)(ws + off); off += (size_t)F * D;      // 45 MB
  int8_t* wdq = (int8_t*)(ws + off); off += (size_t)D * F;      // 45 MB
  int8_t* hq  = (int8_t*)(ws + off); off += (size_t)M * F;      // 45 MB
  float* hbuf = (float*)(ws + off);  off += (size_t)M * F * 4;  // 180 MB
  float* sx   = (float*)(ws + off);  off += (size_t)M * 4;
  float* swg  = (float*)(ws + off);  off += (size_t)F * 4;
  float* swu  = (float*)(ws + off);  off += (size_t)F * 4;
  float* swd  = (float*)(ws + off);  off += (size_t)D * 4;
  float* sh   = (float*)(ws + off);  off += (size_t)M * 4;
  int*   hmax = (int*)(ws + off);    off += (size_t)M * 4;

  hipLaunchKernelGGL(quant_all_kernel, dim3(M + F + F + D), dim3(256), 0,
                     stream, x, Wg, Wu, Wd, xq, wgq, wuq, wdq,
                     sx, swg, swu, swd, hmax);
  hipLaunchKernelGGL(gemm1_kernel, dim3(F / BN, M / BM), dim3(256), 0, stream,
                     xq, wgq, wuq, sx, swg, swu, hbuf, hmax, M, F, D);
  hipLaunchKernelGGL(quant_h_kernel, dim3(M), dim3(256), 0, stream,
                     hbuf, hq, sh, hmax, F);
  hipLaunchKernelGGL(gemm2_kernel, dim3(D / BN2, M / BM), dim3(256), 0, stream,
                     hq, wdq, sh, swd, out, M, D, F);
}